// Round 1
// baseline (313.829 us; speedup 1.0000x reference)
//
#include <hip/hip_runtime.h>
#include <math.h>

typedef unsigned short u16;
typedef unsigned int u32;
typedef __attribute__((ext_vector_type(8))) short short8;  // 8 bf16 (4 VGPR)
typedef __attribute__((ext_vector_type(4))) float f32x4;   // MFMA acc

#define DEVI __device__ __forceinline__

DEVI u16 f2bf(float x) {
    union { float f; u32 u; } un; un.f = x;
    u32 u = un.u;
    return (u16)((u + 0x7fffu + ((u >> 16) & 1u)) >> 16);  // RTNE
}
DEVI float bf2f(u16 v) {
    union { u32 u; float f; } un; un.u = ((u32)v) << 16;
    return un.f;
}
DEVI f32x4 mfma_bf16(short8 a, short8 b, f32x4 c) {
    return __builtin_amdgcn_mfma_f32_16x16x32_bf16(a, b, c, 0, 0, 0);
}
// async global->LDS, 16B/lane. LDS dest = wave-uniform base + lane*16.
DEVI void gload_lds16(const void* g, void* l) {
    __builtin_amdgcn_global_load_lds((const __attribute__((address_space(1))) u32*)g,
                                     (__attribute__((address_space(3))) u32*)l,
                                     16, 0, 0);
}

// ---------------- convert fp32 -> bf16 (straight) ----------------
__global__ void k_convert_bf16(const float* __restrict__ in, u16* __restrict__ out, long n) {
    long idx = ((long)blockIdx.x * 256 + threadIdx.x) * 4;
    if (idx >= n) return;
    float4 v = *(const float4*)(in + idx);
    ushort4 o;
    o.x = f2bf(v.x); o.y = f2bf(v.y); o.z = f2bf(v.z); o.w = f2bf(v.w);
    *(ushort4*)(out + idx) = o;
}

// ---------------- transpose fp32[R][C] -> bf16[C][R] ----------------
__global__ void k_transpose_f32_bf16(const float* __restrict__ in, u16* __restrict__ out,
                                     int R, int C) {
    __shared__ u16 tile[64][68];  // [local r][local c], pad keeps 8B align of vec writes
    const int tx = threadIdx.x & 15, ty = threadIdx.x >> 4;
    const long r0 = (long)blockIdx.y * 64, c0 = (long)blockIdx.x * 64;
#pragma unroll
    for (int p = 0; p < 4; ++p) {
        int r = ty + p * 16;
        float4 v = *(const float4*)(in + (r0 + r) * C + c0 + tx * 4);
        ushort4 o;
        o.x = f2bf(v.x); o.y = f2bf(v.y); o.z = f2bf(v.z); o.w = f2bf(v.w);
        *(ushort4*)&tile[r][tx * 4] = o;
    }
    __syncthreads();
#pragma unroll
    for (int p = 0; p < 4; ++p) {
        int rr = ty + p * 16;  // local out-row = local c of input
        ushort4 o;
        o.x = tile[tx * 4 + 0][rr];
        o.y = tile[tx * 4 + 1][rr];
        o.z = tile[tx * 4 + 2][rr];
        o.w = tile[tx * 4 + 3][rr];
        *(ushort4*)(out + (c0 + rr) * R + r0 + tx * 4) = o;
    }
}

// ---------------- batched transpose bf16: v[32][1024][128] -> vT[32][128][1024] ----------------
__global__ void k_transpose_v(const u16* __restrict__ in, u16* __restrict__ out) {
    __shared__ u16 tile[64][68];
    const int tx = threadIdx.x & 15, ty = threadIdx.x >> 4;
    const int bh = blockIdx.z;
    const long ib = (long)bh * 1024 * 128;
    const long ob = (long)bh * 128 * 1024;
    const int r0 = blockIdx.y * 64, c0 = blockIdx.x * 64;  // r over n=1024, c over d=128
#pragma unroll
    for (int p = 0; p < 4; ++p) {
        int r = ty + p * 16;
        ushort4 v = *(const ushort4*)(in + ib + (long)(r0 + r) * 128 + c0 + tx * 4);
        *(ushort4*)&tile[r][tx * 4] = v;
    }
    __syncthreads();
#pragma unroll
    for (int p = 0; p < 4; ++p) {
        int rr = ty + p * 16;
        ushort4 o;
        o.x = tile[tx * 4 + 0][rr];
        o.y = tile[tx * 4 + 1][rr];
        o.z = tile[tx * 4 + 2][rr];
        o.w = tile[tx * 4 + 3][rr];
        *(ushort4*)(out + ob + (long)(c0 + rr) * 1024 + r0 + tx * 4) = o;
    }
}

// ---------------- RoPE in-place on q,k: [32][1024][128] bf16 ----------------
__global__ void k_rope(u16* __restrict__ q, u16* __restrict__ k) {
    const int idx = blockIdx.x * 256 + threadIdx.x;  // < 2^21
    const int i = idx & 63;
    const int pos = (idx >> 6) & 1023;
    const int bh = idx >> 16;
    const long base = ((long)bh * 1024 + pos) * 128;
    // inv_freq = 10000^(-i/64) ; theta = pos * inv_freq
    float inv = exp2f(-(float)i * 0.20762050593045952f);  // log2(10000)/64
    float theta = (float)pos * inv;
    float sv, cv;
    sincosf(theta, &sv, &cv);  // accurate (large-arg reduction)
    {
        float x1 = bf2f(q[base + i]), x2 = bf2f(q[base + i + 64]);
        q[base + i]      = f2bf(x1 * cv - x2 * sv);
        q[base + i + 64] = f2bf(x2 * cv + x1 * sv);
    }
    {
        float x1 = bf2f(k[base + i]), x2 = bf2f(k[base + i + 64]);
        k[base + i]      = f2bf(x1 * cv - x2 * sv);
        k[base + i + 64] = f2bf(x2 * cv + x1 * sv);
    }
}

// ---------------- m97-style bf16 GEMM: C[M,N] = A[M,K] * BT[N,K]^T ----------------
// EPI 0: scatter bf16 into q/k/v per-head buffers. EPI 1: + bias, fp32 store.
template <int EPI>
__global__ __launch_bounds__(256, 2) void k_gemm(const u16* __restrict__ A,
                                                 const u16* __restrict__ BT, int K,
                                                 u16* __restrict__ qb, u16* __restrict__ kb,
                                                 u16* __restrict__ vb, float* __restrict__ out,
                                                 const float* __restrict__ bias) {
    __shared__ u16 As[128 * 64];  // [m 128][k 64]
    __shared__ u16 Bs[128 * 64];  // [n 128][k 64]
    const int tid = threadIdx.x;
    const int lane = tid & 63, wave = tid >> 6;
    const int lm = lane & 15, quad = lane >> 4;
    const int wm = wave >> 1, wn = wave & 1;
    const int bm = blockIdx.x, bn = blockIdx.y;

    f32x4 acc[4][4] = {};

    // staging geometry: chunk = 1KB = 8 rows of 64 bf16 (128B)
    const int srow = lane >> 3;        // 0..7
    const int scol = (lane & 7) * 8;   // element
    const long arow0 = (long)bm * 128;
    const long brow0 = (long)bn * 128;

    for (int k0 = 0; k0 < K; k0 += 64) {
        __syncthreads();  // prev compute done before LDS overwrite
#pragma unroll
        for (int it = 0; it < 4; ++it) {
            int ch = wave * 4 + it;  // wave-uniform
            long r = ch * 8 + srow;
            gload_lds16(A + (arow0 + r) * K + k0 + scol, (char*)As + ch * 1024);
            gload_lds16(BT + (brow0 + r) * K + k0 + scol, (char*)Bs + ch * 1024);
        }
        __syncthreads();  // drains vmcnt, staging visible
#pragma unroll
        for (int ko = 0; ko < 2; ++ko) {
            short8 af[4], bf[4];
#pragma unroll
            for (int i = 0; i < 4; ++i)
                af[i] = *(const short8*)&As[(wm * 64 + i * 16 + lm) * 64 + ko * 32 + quad * 8];
#pragma unroll
            for (int j = 0; j < 4; ++j)
                bf[j] = *(const short8*)&Bs[(wn * 64 + j * 16 + lm) * 64 + ko * 32 + quad * 8];
#pragma unroll
            for (int i = 0; i < 4; ++i)
#pragma unroll
                for (int j = 0; j < 4; ++j)
                    acc[i][j] = mfma_bf16(af[i], bf[j], acc[i][j]);
        }
    }

    if constexpr (EPI == 0) {
        // cols of this block = one (which, head); 6144 = (3,16,128)
        const int which = bn >> 4;
        const int h = bn & 15;
        u16* dst = (which == 0) ? qb : ((which == 1) ? kb : vb);
        const int b = bm >> 3;
        const long hb = ((long)(b * 16 + h)) * 1024;
#pragma unroll
        for (int i = 0; i < 4; ++i) {
            const int row = bm * 128 + wm * 64 + i * 16 + quad * 4;
            const int pos = row & 1023;
#pragma unroll
            for (int r = 0; r < 4; ++r) {
#pragma unroll
                for (int j = 0; j < 4; ++j) {
                    const int dk = wn * 64 + j * 16 + lm;
                    dst[(hb + pos + r) * 128 + dk] = f2bf(acc[i][j][r]);
                }
            }
        }
    } else {
        float bv[4];
#pragma unroll
        for (int j = 0; j < 4; ++j) bv[j] = bias[bn * 128 + wn * 64 + j * 16 + lm];
#pragma unroll
        for (int i = 0; i < 4; ++i) {
#pragma unroll
            for (int r = 0; r < 4; ++r) {
                const int row = bm * 128 + wm * 64 + i * 16 + quad * 4 + r;
#pragma unroll
                for (int j = 0; j < 4; ++j) {
                    const int col = bn * 128 + wn * 64 + j * 16 + lm;
                    out[(long)row * 2048 + col] = acc[i][j][r] + bv[j];
                }
            }
        }
    }
}

// ---------------- flash attention (causal), S^T = K*Q^T trick ----------------
// q,k: [32][1024][128] bf16 (roped); vT: [32][128][1024] bf16
// R out: [2][1024][2048] bf16, col = h*128 + dk
__global__ __launch_bounds__(256, 2) void k_flash(const u16* __restrict__ Q,
                                                  const u16* __restrict__ Kb,
                                                  const u16* __restrict__ VT,
                                                  u16* __restrict__ R) {
    __shared__ u16 Qs[64 * 128];  // [q 64][d 128]
    __shared__ u16 Ks[64 * 128];  // [key 64][d 128]
    __shared__ u16 Vs[128 * 64];  // [d 128][key 64]
    __shared__ u16 Ps[64 * 72];   // [q 64][key 64 +8 pad]
    const int tid = threadIdx.x;
    const int lane = tid & 63, wave = tid >> 6;
    const int lm = lane & 15, quad = lane >> 4;
    const int qt = blockIdx.x, bh = blockIdx.y;
    const long qkbase = (long)bh * 1024 * 128;
    const long vtbase = (long)bh * 128 * 1024;
    const int q0 = qt * 64;

    // stage Q tile once: rows 256B, chunk = 4 rows
    {
        const int r = lane >> 4, cb = (lane & 15) * 8;
#pragma unroll
        for (int it = 0; it < 4; ++it) {
            int ch = wave * 4 + it;
            gload_lds16(Q + qkbase + (long)(q0 + ch * 4 + r) * 128 + cb, (char*)Qs + ch * 1024);
        }
    }

    f32x4 o_acc[8] = {};
    float m_i = -INFINITY, l_i = 0.f;
    const float cl2e = 0.08838834764831845f * 1.4426950408889634f;  // 1/sqrt(128)*log2(e)

    for (int kt = 0; kt <= qt; ++kt) {
        __syncthreads();  // prev iter done (also covers Q staging on iter 0)
        {
            const int r4 = lane >> 4, cb4 = (lane & 15) * 8;
            const int r8 = lane >> 3, cb8 = (lane & 7) * 8;
#pragma unroll
            for (int it = 0; it < 4; ++it) {
                int ch = wave * 4 + it;
                gload_lds16(Kb + qkbase + (long)(kt * 64 + ch * 4 + r4) * 128 + cb4,
                            (char*)Ks + ch * 1024);
                gload_lds16(VT + vtbase + (long)(ch * 8 + r8) * 1024 + kt * 64 + cb8,
                            (char*)Vs + ch * 1024);
            }
        }
        __syncthreads();

        // S^T[key 64][q 16(this wave)] = K * Q^T
        f32x4 s_acc[4] = {};
#pragma unroll
        for (int kc = 0; kc < 4; ++kc) {
            short8 bq = *(const short8*)&Qs[(wave * 16 + lm) * 128 + kc * 32 + quad * 8];
#pragma unroll
            for (int mi = 0; mi < 4; ++mi) {
                short8 ak = *(const short8*)&Ks[(mi * 16 + lm) * 128 + kc * 32 + quad * 8];
                s_acc[mi] = mfma_bf16(ak, bq, s_acc[mi]);
            }
        }
        // scaled log2 domain + causal mask
        const int qg = q0 + wave * 16 + lm;  // this lane's q column
        float t[4][4];
        float cmax = -INFINITY;
#pragma unroll
        for (int mi = 0; mi < 4; ++mi)
#pragma unroll
            for (int r = 0; r < 4; ++r) {
                int kg = kt * 64 + mi * 16 + quad * 4 + r;
                float val = (kg <= qg) ? s_acc[mi][r] * cl2e : -INFINITY;
                t[mi][r] = val;
                cmax = fmaxf(cmax, val);
            }
        cmax = fmaxf(cmax, __shfl_xor(cmax, 16));
        cmax = fmaxf(cmax, __shfl_xor(cmax, 32));
        float m_new = fmaxf(m_i, cmax);
        float alpha = exp2f(m_i - m_new);
        float csum = 0.f;
#pragma unroll
        for (int mi = 0; mi < 4; ++mi)
#pragma unroll
            for (int r = 0; r < 4; ++r) {
                float p = exp2f(t[mi][r] - m_new);
                t[mi][r] = p;
                csum += p;
            }
        csum += __shfl_xor(csum, 16);
        csum += __shfl_xor(csum, 32);
        l_i = l_i * alpha + csum;
        m_i = m_new;
        // P (bf16) -> LDS in A-operand-friendly [q][key] layout
#pragma unroll
        for (int mi = 0; mi < 4; ++mi) {
            ushort4 pk;
            pk.x = f2bf(t[mi][0]); pk.y = f2bf(t[mi][1]);
            pk.z = f2bf(t[mi][2]); pk.w = f2bf(t[mi][3]);
            *(ushort4*)&Ps[(wave * 16 + lm) * 72 + mi * 16 + quad * 4] = pk;
        }
        // rescale O by alpha (alpha lives in q=lm domain; O rows are q=quad*4+r domain)
        float aq[4];
#pragma unroll
        for (int r = 0; r < 4; ++r) aq[r] = __shfl(alpha, quad * 4 + r, 64);
#pragma unroll
        for (int nt = 0; nt < 8; ++nt)
#pragma unroll
            for (int r = 0; r < 4; ++r) o_acc[nt][r] *= aq[r];
        __syncthreads();  // order Ps stores vs vector reads below (alias-safe fence)
        // O[q 16][d 128] += P[16][64] * V[64][128]
#pragma unroll
        for (int kc = 0; kc < 2; ++kc) {
            short8 ap = *(const short8*)&Ps[(wave * 16 + lm) * 72 + kc * 32 + quad * 8];
#pragma unroll
            for (int nt = 0; nt < 8; ++nt) {
                short8 bv = *(const short8*)&Vs[(nt * 16 + lm) * 64 + kc * 32 + quad * 8];
                o_acc[nt] = mfma_bf16(ap, bv, o_acc[nt]);
            }
        }
    }
    // epilogue: /= l, store bf16 to r buffer [b][pos][h*128+dk]
    float lq[4];
#pragma unroll
    for (int r = 0; r < 4; ++r) lq[r] = __shfl(l_i, quad * 4 + r, 64);
    const int b = bh >> 4, h = bh & 15;
#pragma unroll
    for (int nt = 0; nt < 8; ++nt)
#pragma unroll
        for (int r = 0; r < 4; ++r) {
            const int pos = q0 + wave * 16 + quad * 4 + r;
            const int col = h * 128 + nt * 16 + lm;
            R[((long)b * 1024 + pos) * 2048 + col] = f2bf(o_acc[nt][r] / lq[r]);
        }
}

extern "C" void kernel_launch(void* const* d_in, const int* in_sizes, int n_in,
                              void* d_out, int out_size, void* d_ws, size_t ws_size,
                              hipStream_t stream) {
    const float* x    = (const float*)d_in[0];
    // d_in[1] = causal mask (tril) — structure hardcoded
    const float* Wqkv = (const float*)d_in[2];
    const float* Wout = (const float*)d_in[3];
    const float* bout = (const float*)d_in[4];
    float* out = (float*)d_out;

    char* ws = (char*)d_ws;
    // layout (64MB total), with lifetime-based reuse:
    u16* x_bf  = (u16*)(ws);                 // 8MB; dead after qkv GEMM
    u16* rbuf  = x_bf;                       // reuse: written by flash (after qkv GEMM)
    u16* WqkvT = (u16*)(ws + (8L << 20));    // 24MB; dead after qkv GEMM
    u16* vT    = WqkvT;                      // reuse first 8MB: written after qkv GEMM
    u16* WoutT = (u16*)(ws + (32L << 20));   // 8MB
    u16* qbuf  = (u16*)(ws + (40L << 20));   // 8MB
    u16* kbuf  = (u16*)(ws + (48L << 20));   // 8MB
    u16* vbuf  = (u16*)(ws + (56L << 20));   // 8MB

    k_convert_bf16<<<4096, 256, 0, stream>>>(x, x_bf, 4194304);
    k_transpose_f32_bf16<<<dim3(96, 32), 256, 0, stream>>>(Wqkv, WqkvT, 2048, 6144);
    k_transpose_f32_bf16<<<dim3(32, 32), 256, 0, stream>>>(Wout, WoutT, 2048, 2048);
    // qkv = x @ Wqkv, scatter to q/k/v head buffers
    k_gemm<0><<<dim3(16, 48), 256, 0, stream>>>(x_bf, WqkvT, 2048, qbuf, kbuf, vbuf,
                                                nullptr, nullptr);
    k_rope<<<8192, 256, 0, stream>>>(qbuf, kbuf);
    k_transpose_v<<<dim3(2, 16, 32), 256, 0, stream>>>(vbuf, vT);
    k_flash<<<dim3(16, 32), 256, 0, stream>>>(qbuf, kbuf, vT, rbuf);
    // out = r @ Wout + bout
    k_gemm<1><<<dim3(16, 16), 256, 0, stream>>>(rbuf, WoutT, 2048, nullptr, nullptr, nullptr,
                                                out, bout);
}

// Round 2
// 259.070 us; speedup vs baseline: 1.2114x; 1.2114x over previous
//
#include <hip/hip_runtime.h>
#include <math.h>

typedef unsigned short u16;
typedef unsigned int u32;
typedef __attribute__((ext_vector_type(8))) short short8;  // 8 bf16 (4 VGPR)
typedef __attribute__((ext_vector_type(4))) float f32x4;   // MFMA acc

#define DEVI __device__ __forceinline__

DEVI u16 f2bf(float x) {
    union { float f; u32 u; } un; un.f = x;
    u32 u = un.u;
    return (u16)((u + 0x7fffu + ((u >> 16) & 1u)) >> 16);  // RTNE
}
DEVI float bf2f(u16 v) {
    union { u32 u; float f; } un; un.u = ((u32)v) << 16;
    return un.f;
}
DEVI f32x4 mfma_bf16(short8 a, short8 b, f32x4 c) {
    return __builtin_amdgcn_mfma_f32_16x16x32_bf16(a, b, c, 0, 0, 0);
}
// async global->LDS, 16B/lane. LDS dest = wave-uniform base + lane*16.
DEVI void gload_lds16(const void* g, void* l) {
    __builtin_amdgcn_global_load_lds((const __attribute__((address_space(1))) u32*)g,
                                     (__attribute__((address_space(3))) u32*)l,
                                     16, 0, 0);
}

// ---------------- convert fp32 -> bf16 (straight) ----------------
__global__ void k_convert_bf16(const float* __restrict__ in, u16* __restrict__ out, long n) {
    long idx = ((long)blockIdx.x * 256 + threadIdx.x) * 4;
    if (idx >= n) return;
    float4 v = *(const float4*)(in + idx);
    ushort4 o;
    o.x = f2bf(v.x); o.y = f2bf(v.y); o.z = f2bf(v.z); o.w = f2bf(v.w);
    *(ushort4*)(out + idx) = o;
}

// ---------------- transpose fp32[R][C] -> bf16[C][R] ----------------
__global__ void k_transpose_f32_bf16(const float* __restrict__ in, u16* __restrict__ out,
                                     int R, int C) {
    __shared__ u16 tile[64][68];
    const int tx = threadIdx.x & 15, ty = threadIdx.x >> 4;
    const long r0 = (long)blockIdx.y * 64, c0 = (long)blockIdx.x * 64;
#pragma unroll
    for (int p = 0; p < 4; ++p) {
        int r = ty + p * 16;
        float4 v = *(const float4*)(in + (r0 + r) * C + c0 + tx * 4);
        ushort4 o;
        o.x = f2bf(v.x); o.y = f2bf(v.y); o.z = f2bf(v.z); o.w = f2bf(v.w);
        *(ushort4*)&tile[r][tx * 4] = o;
    }
    __syncthreads();
#pragma unroll
    for (int p = 0; p < 4; ++p) {
        int rr = ty + p * 16;
        ushort4 o;
        o.x = tile[tx * 4 + 0][rr];
        o.y = tile[tx * 4 + 1][rr];
        o.z = tile[tx * 4 + 2][rr];
        o.w = tile[tx * 4 + 3][rr];
        *(ushort4*)(out + (c0 + rr) * R + r0 + tx * 4) = o;
    }
}

// ---------------- batched transpose bf16: v[32][1024][128] -> vT[32][128][1024] ----------------
__global__ void k_transpose_v(const u16* __restrict__ in, u16* __restrict__ out) {
    __shared__ u16 tile[64][68];
    const int tx = threadIdx.x & 15, ty = threadIdx.x >> 4;
    const int bh = blockIdx.z;
    const long ib = (long)bh * 1024 * 128;
    const long ob = (long)bh * 128 * 1024;
    const int r0 = blockIdx.y * 64, c0 = blockIdx.x * 64;
#pragma unroll
    for (int p = 0; p < 4; ++p) {
        int r = ty + p * 16;
        ushort4 v = *(const ushort4*)(in + ib + (long)(r0 + r) * 128 + c0 + tx * 4);
        *(ushort4*)&tile[r][tx * 4] = v;
    }
    __syncthreads();
#pragma unroll
    for (int p = 0; p < 4; ++p) {
        int rr = ty + p * 16;
        ushort4 o;
        o.x = tile[tx * 4 + 0][rr];
        o.y = tile[tx * 4 + 1][rr];
        o.z = tile[tx * 4 + 2][rr];
        o.w = tile[tx * 4 + 3][rr];
        *(ushort4*)(out + ob + (long)(c0 + rr) * 1024 + r0 + tx * 4) = o;
    }
}

// ---------------- RoPE in-place on q,k: [32][1024][128] bf16 ----------------
__global__ void k_rope(u16* __restrict__ q, u16* __restrict__ k) {
    const int idx = blockIdx.x * 256 + threadIdx.x;
    const int i = idx & 63;
    const int pos = (idx >> 6) & 1023;
    const int bh = idx >> 16;
    const long base = ((long)bh * 1024 + pos) * 128;
    float inv = exp2f(-(float)i * 0.20762050593045952f);  // log2(10000)/64
    float theta = (float)pos * inv;
    float sv, cv;
    sincosf(theta, &sv, &cv);
    {
        float x1 = bf2f(q[base + i]), x2 = bf2f(q[base + i + 64]);
        q[base + i]      = f2bf(x1 * cv - x2 * sv);
        q[base + i + 64] = f2bf(x2 * cv + x1 * sv);
    }
    {
        float x1 = bf2f(k[base + i]), x2 = bf2f(k[base + i + 64]);
        k[base + i]      = f2bf(x1 * cv - x2 * sv);
        k[base + i + 64] = f2bf(x2 * cv + x1 * sv);
    }
}

// ---------------- m97-style bf16 GEMM, XOR-swizzled LDS ----------------
// LDS invariant: phys 16B-chunk pc of row r holds logical chunk pc ^ (r & 7).
// C[M,N] = A[M,K] * BT[N,K]^T.  EPI 0: scatter bf16 q/k/v.  EPI 1: +bias fp32.
template <int EPI>
__global__ __launch_bounds__(256, 2) void k_gemm(const u16* __restrict__ A,
                                                 const u16* __restrict__ BT, int K,
                                                 u16* __restrict__ qb, u16* __restrict__ kb,
                                                 u16* __restrict__ vb, float* __restrict__ out,
                                                 const float* __restrict__ bias) {
    __shared__ u16 As[128 * 64];  // [m 128][k 64], swizzled
    __shared__ u16 Bs[128 * 64];  // [n 128][k 64], swizzled
    const int tid = threadIdx.x;
    const int lane = tid & 63, wave = tid >> 6;
    const int lm = lane & 15, quad = lane >> 4;
    const int wm = wave >> 1, wn = wave & 1;
    const int bm = blockIdx.x, bn = blockIdx.y;

    f32x4 acc[4][4] = {};

    // staging: chunk ch = 1KB = 8 rows x 64 cols. lane l -> phys (row ch*8+(l>>3), chunk l&7)
    const int srow = lane >> 3;                         // 0..7
    const int scb = (lane & 7) ^ srow;                  // logical chunk = phys ^ (row&7)
    const long arow0 = (long)bm * 128;
    const long brow0 = (long)bn * 128;

    for (int k0 = 0; k0 < K; k0 += 64) {
        __syncthreads();
#pragma unroll
        for (int it = 0; it < 4; ++it) {
            int ch = wave * 4 + it;
            long r = ch * 8 + srow;
            gload_lds16(A + (arow0 + r) * K + k0 + scb * 8, (char*)As + ch * 1024);
            gload_lds16(BT + (brow0 + r) * K + k0 + scb * 8, (char*)Bs + ch * 1024);
        }
        __syncthreads();
#pragma unroll
        for (int ko = 0; ko < 2; ++ko) {
            short8 af[4], bf[4];
#pragma unroll
            for (int i = 0; i < 4; ++i) {
                int row = wm * 64 + i * 16 + lm;
                int pc = (ko * 4 + quad) ^ (lm & 7);
                af[i] = *(const short8*)&As[row * 64 + pc * 8];
            }
#pragma unroll
            for (int j = 0; j < 4; ++j) {
                int row = wn * 64 + j * 16 + lm;
                int pc = (ko * 4 + quad) ^ (lm & 7);
                bf[j] = *(const short8*)&Bs[row * 64 + pc * 8];
            }
#pragma unroll
            for (int i = 0; i < 4; ++i)
#pragma unroll
                for (int j = 0; j < 4; ++j)
                    acc[i][j] = mfma_bf16(af[i], bf[j], acc[i][j]);
        }
    }

    if constexpr (EPI == 0) {
        const int which = bn >> 4;
        const int h = bn & 15;
        u16* dst = (which == 0) ? qb : ((which == 1) ? kb : vb);
        const int b = bm >> 3;
        const long hb = ((long)(b * 16 + h)) * 1024;
#pragma unroll
        for (int i = 0; i < 4; ++i) {
            const int row = bm * 128 + wm * 64 + i * 16 + quad * 4;
            const int pos = row & 1023;
#pragma unroll
            for (int r = 0; r < 4; ++r) {
#pragma unroll
                for (int j = 0; j < 4; ++j) {
                    const int dk = wn * 64 + j * 16 + lm;
                    dst[(hb + pos + r) * 128 + dk] = f2bf(acc[i][j][r]);
                }
            }
        }
    } else {
        float bv[4];
#pragma unroll
        for (int j = 0; j < 4; ++j) bv[j] = bias[bn * 128 + wn * 64 + j * 16 + lm];
#pragma unroll
        for (int i = 0; i < 4; ++i) {
#pragma unroll
            for (int r = 0; r < 4; ++r) {
                const int row = bm * 128 + wm * 64 + i * 16 + quad * 4 + r;
#pragma unroll
                for (int j = 0; j < 4; ++j) {
                    const int col = bn * 128 + wn * 64 + j * 16 + lm;
                    out[(long)row * 2048 + col] = acc[i][j][r] + bv[j];
                }
            }
        }
    }
}

// ---------------- flash attention (causal), S^T = K*Q^T, swizzled LDS ----------------
// Q in registers; Ks swizzled mask 15 (256B rows); Vs swizzled mask 7 (128B rows).
// Balanced grid: block id -> (bh, qt) with co-resident pairs summing to 17 units.
__global__ __launch_bounds__(256, 2) void k_flash(const u16* __restrict__ Q,
                                                  const u16* __restrict__ Kb,
                                                  const u16* __restrict__ VT,
                                                  u16* __restrict__ R) {
    __shared__ u16 Ks[64 * 128];  // [key 64][d 128], swizzled mask 15
    __shared__ u16 Vs[128 * 64];  // [d 128][key 64], swizzled mask 7
    __shared__ u16 Ps[64 * 72];   // [q 64][key 64 + 8 pad]
    const int tid = threadIdx.x;
    const int lane = tid & 63, wave = tid >> 6;
    const int lm = lane & 15, quad = lane >> 4;
    // balanced mapping: g=0 -> qt=s (light), g=1 -> qt=15-s (heavy)
    const int id = blockIdx.x;
    const int g = id >> 8, rem = id & 255;
    const int bh = rem >> 3, s = rem & 7;
    const int qt = g ? (15 - s) : s;
    const long qkbase = (long)bh * 1024 * 128;
    const long vtbase = (long)bh * 128 * 1024;
    const int q0 = qt * 64;

    // Q fragment in registers: rows q0 + wave*16 + lm, all 128 cols
    short8 qf[4];
    {
        const u16* qrow = Q + qkbase + (long)(q0 + wave * 16 + lm) * 128 + quad * 8;
#pragma unroll
        for (int kc = 0; kc < 4; ++kc) qf[kc] = *(const short8*)(qrow + kc * 32);
    }

    f32x4 o_acc[8] = {};
    float m_i = -INFINITY, l_i = 0.f;
    const float cl2e = 0.08838834764831845f * 1.4426950408889634f;  // 1/sqrt(128)*log2(e)

    // staging geometry
    const int kr = lane >> 4;                   // 0..3 (Ks: 4 rows/chunk)
    const int kcb = (lane & 15) ^ kr;           // Ks logical chunk (mask 15; ch*4 ≡ 0 mod 16... see note)
    const int vr = lane >> 3;                   // 0..7 (Vs: 8 rows/chunk)
    const int vcb = (lane & 7) ^ vr;            // Vs logical chunk partial (needs ch*8 term? ch*8&7=0)

    for (int kt = 0; kt <= qt; ++kt) {
        __syncthreads();  // prior iter's LDS reads done
        {
#pragma unroll
            for (int it = 0; it < 4; ++it) {
                int ch = wave * 4 + it;
                // Ks: row_p = ch*4 + kr; row_p & 15 = (ch*4 + kr) & 15
                int krow = ch * 4 + kr;
                int kchunk = (lane & 15) ^ (krow & 15);
                gload_lds16(Kb + qkbase + (long)(kt * 64 + krow) * 128 + kchunk * 8,
                            (char*)Ks + ch * 1024);
                // Vs: row_p = ch*8 + vr; row_p & 7 = vr
                int vrow = ch * 8 + vr;
                gload_lds16(VT + vtbase + (long)vrow * 1024 + kt * 64 + vcb * 8,
                            (char*)Vs + ch * 1024);
            }
        }
        __syncthreads();  // staging visible

        // S^T[key 64][q 16(this wave)] = K * Q^T
        f32x4 s_acc[4] = {};
#pragma unroll
        for (int kc = 0; kc < 4; ++kc) {
#pragma unroll
            for (int mi = 0; mi < 4; ++mi) {
                int row = mi * 16 + lm;
                int pc = (kc * 4 + quad) ^ lm;  // mask 15, row&15 = lm
                short8 ak = *(const short8*)&Ks[row * 128 + pc * 8];
                s_acc[mi] = mfma_bf16(ak, qf[kc], s_acc[mi]);
            }
        }
        // softmax (scaled log2 domain) + causal mask
        const int qg = q0 + wave * 16 + lm;
        float t[4][4];
        float cmax = -INFINITY;
#pragma unroll
        for (int mi = 0; mi < 4; ++mi)
#pragma unroll
            for (int r = 0; r < 4; ++r) {
                int kg = kt * 64 + mi * 16 + quad * 4 + r;
                float val = (kg <= qg) ? s_acc[mi][r] * cl2e : -INFINITY;
                t[mi][r] = val;
                cmax = fmaxf(cmax, val);
            }
        cmax = fmaxf(cmax, __shfl_xor(cmax, 16));
        cmax = fmaxf(cmax, __shfl_xor(cmax, 32));
        float m_new = fmaxf(m_i, cmax);
        float alpha = exp2f(m_i - m_new);
        float csum = 0.f;
#pragma unroll
        for (int mi = 0; mi < 4; ++mi)
#pragma unroll
            for (int r = 0; r < 4; ++r) {
                float p = exp2f(t[mi][r] - m_new);
                t[mi][r] = p;
                csum += p;
            }
        csum += __shfl_xor(csum, 16);
        csum += __shfl_xor(csum, 32);
        l_i = l_i * alpha + csum;
        m_i = m_new;
        // P -> LDS [q][key] (this wave writes & reads only its own 16 rows; DS in-order)
#pragma unroll
        for (int mi = 0; mi < 4; ++mi) {
            ushort4 pk;
            pk.x = f2bf(t[mi][0]); pk.y = f2bf(t[mi][1]);
            pk.z = f2bf(t[mi][2]); pk.w = f2bf(t[mi][3]);
            *(ushort4*)&Ps[(wave * 16 + lm) * 72 + mi * 16 + quad * 4] = pk;
        }
        // rescale O by alpha (alpha in q=lm domain; O rows in q=quad*4+r domain)
        float aq[4];
#pragma unroll
        for (int r = 0; r < 4; ++r) aq[r] = __shfl(alpha, quad * 4 + r, 64);
#pragma unroll
        for (int nt = 0; nt < 8; ++nt)
#pragma unroll
            for (int r = 0; r < 4; ++r) o_acc[nt][r] *= aq[r];
        // O[q 16][d 128] += P[16][64] * V[64][128]   (no barrier: same-wave Ps RAW)
#pragma unroll
        for (int kc = 0; kc < 2; ++kc) {
            short8 ap = *(const short8*)&Ps[(wave * 16 + lm) * 72 + kc * 32 + quad * 8];
#pragma unroll
            for (int nt = 0; nt < 8; ++nt) {
                int row = nt * 16 + lm;
                int pc = (kc * 4 + quad) ^ (lm & 7);
                short8 bv = *(const short8*)&Vs[row * 64 + pc * 8];
                o_acc[nt] = mfma_bf16(ap, bv, o_acc[nt]);
            }
        }
    }
    // epilogue: /= l, store bf16 to r buffer [b][pos][h*128+dk]
    float lq[4];
#pragma unroll
    for (int r = 0; r < 4; ++r) lq[r] = __shfl(l_i, quad * 4 + r, 64);
    const int b = bh >> 4, h = bh & 15;
#pragma unroll
    for (int nt = 0; nt < 8; ++nt)
#pragma unroll
        for (int r = 0; r < 4; ++r) {
            const int pos = q0 + wave * 16 + quad * 4 + r;
            const int col = h * 128 + nt * 16 + lm;
            R[((long)b * 1024 + pos) * 2048 + col] = f2bf(o_acc[nt][r] / lq[r]);
        }
}

extern "C" void kernel_launch(void* const* d_in, const int* in_sizes, int n_in,
                              void* d_out, int out_size, void* d_ws, size_t ws_size,
                              hipStream_t stream) {
    const float* x    = (const float*)d_in[0];
    const float* Wqkv = (const float*)d_in[2];
    const float* Wout = (const float*)d_in[3];
    const float* bout = (const float*)d_in[4];
    float* out = (float*)d_out;

    char* ws = (char*)d_ws;
    u16* x_bf  = (u16*)(ws);                 // 8MB; dead after qkv GEMM
    u16* rbuf  = x_bf;                       // reuse: written by flash
    u16* WqkvT = (u16*)(ws + (8L << 20));    // 24MB; dead after qkv GEMM
    u16* vT    = WqkvT;                      // reuse first 8MB after qkv GEMM
    u16* WoutT = (u16*)(ws + (32L << 20));   // 8MB
    u16* qbuf  = (u16*)(ws + (40L << 20));   // 8MB
    u16* kbuf  = (u16*)(ws + (48L << 20));   // 8MB
    u16* vbuf  = (u16*)(ws + (56L << 20));   // 8MB

    k_convert_bf16<<<4096, 256, 0, stream>>>(x, x_bf, 4194304);
    k_transpose_f32_bf16<<<dim3(96, 32), 256, 0, stream>>>(Wqkv, WqkvT, 2048, 6144);
    k_transpose_f32_bf16<<<dim3(32, 32), 256, 0, stream>>>(Wout, WoutT, 2048, 2048);
    k_gemm<0><<<dim3(16, 48), 256, 0, stream>>>(x_bf, WqkvT, 2048, qbuf, kbuf, vbuf,
                                                nullptr, nullptr);
    k_rope<<<8192, 256, 0, stream>>>(qbuf, kbuf);
    k_transpose_v<<<dim3(2, 16, 32), 256, 0, stream>>>(vbuf, vT);
    k_flash<<<512, 256, 0, stream>>>(qbuf, kbuf, vT, rbuf);
    k_gemm<1><<<dim3(16, 16), 256, 0, stream>>>(rbuf, WoutT, 2048, nullptr, nullptr, nullptr,
                                                out, bout);
}

// Round 3
// 256.340 us; speedup vs baseline: 1.2243x; 1.0106x over previous
//
#include <hip/hip_runtime.h>
#include <math.h>

typedef unsigned short u16;
typedef unsigned int u32;
typedef __attribute__((ext_vector_type(8))) short short8;  // 8 bf16 (4 VGPR)
typedef __attribute__((ext_vector_type(4))) float f32x4;   // MFMA acc

#define DEVI __device__ __forceinline__

DEVI u16 f2bf(float x) {
    union { float f; u32 u; } un; un.f = x;
    u32 u = un.u;
    return (u16)((u + 0x7fffu + ((u >> 16) & 1u)) >> 16);  // RTNE
}
DEVI float bf2f(u16 v) {
    union { u32 u; float f; } un; un.u = ((u32)v) << 16;
    return un.f;
}
DEVI f32x4 mfma_bf16(short8 a, short8 b, f32x4 c) {
    return __builtin_amdgcn_mfma_f32_16x16x32_bf16(a, b, c, 0, 0, 0);
}
// async global->LDS, 16B/lane. LDS dest = wave-uniform base + lane*16.
DEVI void gload_lds16(const void* g, void* l) {
    __builtin_amdgcn_global_load_lds((const __attribute__((address_space(1))) u32*)g,
                                     (__attribute__((address_space(3))) u32*)l,
                                     16, 0, 0);
}

// ---------------- fused prep: x->bf16 convert + Wqkv^T + Wout^T ----------------
// blocks [0,4096): convert; [4096,7168): Wqkv 2048x6144 -> T; [7168,8192): Wout 2048x2048 -> T
__global__ void k_prep(const float* __restrict__ x, const float* __restrict__ Wqkv,
                       const float* __restrict__ Wout, u16* __restrict__ x_bf,
                       u16* __restrict__ WqkvT, u16* __restrict__ WoutT) {
    __shared__ u16 tile[64][68];
    const int bid = blockIdx.x;
    if (bid < 4096) {
        long idx = ((long)bid * 256 + threadIdx.x) * 4;
        float4 v = *(const float4*)(x + idx);
        ushort4 o;
        o.x = f2bf(v.x); o.y = f2bf(v.y); o.z = f2bf(v.z); o.w = f2bf(v.w);
        *(ushort4*)(x_bf + idx) = o;
        return;
    }
    const float* in;
    u16* out;
    int R, C, bx, by;
    if (bid < 7168) {
        int lb = bid - 4096;
        in = Wqkv; out = WqkvT; R = 2048; C = 6144;
        bx = lb % 96; by = lb / 96;
    } else {
        int lb = bid - 7168;
        in = Wout; out = WoutT; R = 2048; C = 2048;
        bx = lb & 31; by = lb >> 5;
    }
    const int tx = threadIdx.x & 15, ty = threadIdx.x >> 4;
    const long r0 = (long)by * 64, c0 = (long)bx * 64;
#pragma unroll
    for (int p = 0; p < 4; ++p) {
        int r = ty + p * 16;
        float4 v = *(const float4*)(in + (r0 + r) * C + c0 + tx * 4);
        ushort4 o;
        o.x = f2bf(v.x); o.y = f2bf(v.y); o.z = f2bf(v.z); o.w = f2bf(v.w);
        *(ushort4*)&tile[r][tx * 4] = o;
    }
    __syncthreads();
#pragma unroll
    for (int p = 0; p < 4; ++p) {
        int rr = ty + p * 16;
        ushort4 o;
        o.x = tile[tx * 4 + 0][rr];
        o.y = tile[tx * 4 + 1][rr];
        o.z = tile[tx * 4 + 2][rr];
        o.w = tile[tx * 4 + 3][rr];
        *(ushort4*)(out + (c0 + rr) * R + r0 + tx * 4) = o;
    }
}

// ---------------- m97-style bf16 GEMM, XOR-swizzled LDS ----------------
// C[M,N] = A[M,K] * BT[N,K]^T.
// EPI 0: QKV epilogue — LDS tile round-trip; q/k get RoPE applied, v stored transposed
//        straight into vT[32][128][1024].
// EPI 1: +bias, fp32 store.
template <int EPI>
__global__ __launch_bounds__(256, 2) void k_gemm(const u16* __restrict__ A,
                                                 const u16* __restrict__ BT, int K,
                                                 u16* __restrict__ qb, u16* __restrict__ kb,
                                                 u16* __restrict__ vtb, float* __restrict__ out,
                                                 const float* __restrict__ bias) {
    __shared__ union SM {
        struct { u16 As[128 * 64]; u16 Bs[128 * 64]; } s;  // swizzled staging
        u16 T[128 * 132];                                  // epilogue transpose tile (pad 132)
    } sm;
    const int tid = threadIdx.x;
    const int lane = tid & 63, wave = tid >> 6;
    const int lm = lane & 15, quad = lane >> 4;
    const int wm = wave >> 1, wn = wave & 1;
    const int bm = blockIdx.x, bn = blockIdx.y;

    f32x4 acc[4][4] = {};

    // staging: chunk ch = 1KB = 8 rows x 64 cols; phys chunk pc holds logical pc ^ (row&7)
    const int srow = lane >> 3;
    const int scb = (lane & 7) ^ srow;
    const long arow0 = (long)bm * 128;
    const long brow0 = (long)bn * 128;

    for (int k0 = 0; k0 < K; k0 += 64) {
        __syncthreads();
#pragma unroll
        for (int it = 0; it < 4; ++it) {
            int ch = wave * 4 + it;
            long r = ch * 8 + srow;
            gload_lds16(A + (arow0 + r) * K + k0 + scb * 8, (char*)sm.s.As + ch * 1024);
            gload_lds16(BT + (brow0 + r) * K + k0 + scb * 8, (char*)sm.s.Bs + ch * 1024);
        }
        __syncthreads();
#pragma unroll
        for (int ko = 0; ko < 2; ++ko) {
            short8 af[4], bf[4];
#pragma unroll
            for (int i = 0; i < 4; ++i) {
                int row = wm * 64 + i * 16 + lm;
                int pc = (ko * 4 + quad) ^ (lm & 7);
                af[i] = *(const short8*)&sm.s.As[row * 64 + pc * 8];
            }
#pragma unroll
            for (int j = 0; j < 4; ++j) {
                int row = wn * 64 + j * 16 + lm;
                int pc = (ko * 4 + quad) ^ (lm & 7);
                bf[j] = *(const short8*)&sm.s.Bs[row * 64 + pc * 8];
            }
#pragma unroll
            for (int i = 0; i < 4; ++i)
#pragma unroll
                for (int j = 0; j < 4; ++j)
                    acc[i][j] = mfma_bf16(af[i], bf[j], acc[i][j]);
        }
    }

    if constexpr (EPI == 0) {
        // ---- round-trip the 128x128 tile through LDS ----
        __syncthreads();  // all waves done reading As/Bs
#pragma unroll
        for (int i = 0; i < 4; ++i)
#pragma unroll
            for (int j = 0; j < 4; ++j) {
                const int col = wn * 64 + j * 16 + lm;
#pragma unroll
                for (int r = 0; r < 4; ++r) {
                    const int row = wm * 64 + i * 16 + quad * 4 + r;
                    sm.T[row * 132 + col] = f2bf(acc[i][j][r]);
                }
            }
        __syncthreads();
        const int which = bn >> 4, h = bn & 15, b = bm >> 3;
        const int p0 = (bm & 7) * 128;
        if (which < 2) {
            // RoPE + store to q/k buffer [bh][pos][128]
            u16* dst = which ? kb : qb;
            const long hb = ((long)(b * 16 + h)) * 1024;
#pragma unroll
            for (int c = 0; c < 8; ++c) {
                const int lin = c * 1024 + tid * 4;  // pair space: 128 pos x 64 i
                const int pos_l = lin >> 6;
                const int i0 = lin & 63;  // multiple of 4
                ushort4 cur = *(const ushort4*)&sm.T[pos_l * 132 + i0];
                ushort4 par = *(const ushort4*)&sm.T[pos_l * 132 + i0 + 64];
                const float pg = (float)(p0 + pos_l);
                ushort4 o1, o2;
                const u16* cp = (const u16*)&cur;
                const u16* pp = (const u16*)&par;
                u16* o1p = (u16*)&o1;
                u16* o2p = (u16*)&o2;
#pragma unroll
                for (int e = 0; e < 4; ++e) {
                    float inv = exp2f(-(float)(i0 + e) * 0.20762050593045952f);
                    float sv, cv;
                    sincosf(pg * inv, &sv, &cv);
                    float x1 = bf2f(cp[e]), x2 = bf2f(pp[e]);
                    o1p[e] = f2bf(x1 * cv - x2 * sv);
                    o2p[e] = f2bf(x2 * cv + x1 * sv);
                }
                const long rowb = (hb + p0 + pos_l) * 128;
                *(ushort4*)(dst + rowb + i0) = o1;
                *(ushort4*)(dst + rowb + i0 + 64) = o2;
            }
        } else {
            // V: store transposed into vT[32][128][1024]
            const long vrow = ((long)(b * 16 + h)) * 128;
#pragma unroll
            for (int c = 0; c < 8; ++c) {
                const int lin = c * 2048 + tid * 8;
                const int dk = lin >> 7;
                const int ps = lin & 127;  // multiple of 8
                ushort4 o1, o2;
                u16* o1p = (u16*)&o1;
                u16* o2p = (u16*)&o2;
#pragma unroll
                for (int e = 0; e < 4; ++e) {
                    o1p[e] = sm.T[(ps + e) * 132 + dk];
                    o2p[e] = sm.T[(ps + 4 + e) * 132 + dk];
                }
                u16* dst = vtb + (vrow + dk) * 1024 + p0 + ps;
                *(ushort4*)dst = o1;
                *(ushort4*)(dst + 4) = o2;
            }
        }
    } else {
        float bv[4];
#pragma unroll
        for (int j = 0; j < 4; ++j) bv[j] = bias[bn * 128 + wn * 64 + j * 16 + lm];
#pragma unroll
        for (int i = 0; i < 4; ++i) {
#pragma unroll
            for (int r = 0; r < 4; ++r) {
                const int row = bm * 128 + wm * 64 + i * 16 + quad * 4 + r;
#pragma unroll
                for (int j = 0; j < 4; ++j) {
                    const int col = bn * 128 + wn * 64 + j * 16 + lm;
                    out[(long)row * 2048 + col] = acc[i][j][r] + bv[j];
                }
            }
        }
    }
}

// ---------------- flash attention (causal), S^T = K*Q^T, swizzled LDS ----------------
__global__ __launch_bounds__(256, 2) void k_flash(const u16* __restrict__ Q,
                                                  const u16* __restrict__ Kb,
                                                  const u16* __restrict__ VT,
                                                  u16* __restrict__ R) {
    __shared__ u16 Ks[64 * 128];  // [key 64][d 128], swizzled mask 15
    __shared__ u16 Vs[128 * 64];  // [d 128][key 64], swizzled mask 7
    __shared__ u16 Ps[64 * 72];   // [q 64][key 64 + 8 pad]
    const int tid = threadIdx.x;
    const int lane = tid & 63, wave = tid >> 6;
    const int lm = lane & 15, quad = lane >> 4;
    // balanced mapping: co-resident pairs sum to 17 k-tile units
    const int id = blockIdx.x;
    const int g = id >> 8, rem = id & 255;
    const int bh = rem >> 3, s = rem & 7;
    const int qt = g ? (15 - s) : s;
    const long qkbase = (long)bh * 1024 * 128;
    const long vtbase = (long)bh * 128 * 1024;
    const int q0 = qt * 64;

    // Q fragment in registers
    short8 qf[4];
    {
        const u16* qrow = Q + qkbase + (long)(q0 + wave * 16 + lm) * 128 + quad * 8;
#pragma unroll
        for (int kc = 0; kc < 4; ++kc) qf[kc] = *(const short8*)(qrow + kc * 32);
    }

    f32x4 o_acc[8] = {};
    float m_i = -INFINITY, l_i = 0.f;
    const float cl2e = 0.08838834764831845f * 1.4426950408889634f;  // 1/sqrt(128)*log2(e)

    const int kr = lane >> 4;          // Ks: 4 rows/chunk
    const int vr = lane >> 3;          // Vs: 8 rows/chunk
    const int vcb = (lane & 7) ^ vr;   // Vs logical chunk (mask 7)

    for (int kt = 0; kt <= qt; ++kt) {
        __syncthreads();
        {
#pragma unroll
            for (int it = 0; it < 4; ++it) {
                int ch = wave * 4 + it;
                int krow = ch * 4 + kr;
                int kchunk = (lane & 15) ^ (krow & 15);
                gload_lds16(Kb + qkbase + (long)(kt * 64 + krow) * 128 + kchunk * 8,
                            (char*)Ks + ch * 1024);
                int vrow = ch * 8 + vr;
                gload_lds16(VT + vtbase + (long)vrow * 1024 + kt * 64 + vcb * 8,
                            (char*)Vs + ch * 1024);
            }
        }
        __syncthreads();

        // S^T[key 64][q 16] = K * Q^T
        f32x4 s_acc[4] = {};
#pragma unroll
        for (int kc = 0; kc < 4; ++kc) {
#pragma unroll
            for (int mi = 0; mi < 4; ++mi) {
                int row = mi * 16 + lm;
                int pc = (kc * 4 + quad) ^ lm;
                short8 ak = *(const short8*)&Ks[row * 128 + pc * 8];
                s_acc[mi] = mfma_bf16(ak, qf[kc], s_acc[mi]);
            }
        }
        // softmax (log2 domain) + causal mask
        const int qg = q0 + wave * 16 + lm;
        float t[4][4];
        float cmax = -INFINITY;
#pragma unroll
        for (int mi = 0; mi < 4; ++mi)
#pragma unroll
            for (int r = 0; r < 4; ++r) {
                int kg = kt * 64 + mi * 16 + quad * 4 + r;
                float val = (kg <= qg) ? s_acc[mi][r] * cl2e : -INFINITY;
                t[mi][r] = val;
                cmax = fmaxf(cmax, val);
            }
        cmax = fmaxf(cmax, __shfl_xor(cmax, 16));
        cmax = fmaxf(cmax, __shfl_xor(cmax, 32));
        float m_new = fmaxf(m_i, cmax);
        float alpha = exp2f(m_i - m_new);
        float csum = 0.f;
#pragma unroll
        for (int mi = 0; mi < 4; ++mi)
#pragma unroll
            for (int r = 0; r < 4; ++r) {
                float p = exp2f(t[mi][r] - m_new);
                t[mi][r] = p;
                csum += p;
            }
        csum += __shfl_xor(csum, 16);
        csum += __shfl_xor(csum, 32);
        l_i = l_i * alpha + csum;
        m_i = m_new;
#pragma unroll
        for (int mi = 0; mi < 4; ++mi) {
            ushort4 pk;
            pk.x = f2bf(t[mi][0]); pk.y = f2bf(t[mi][1]);
            pk.z = f2bf(t[mi][2]); pk.w = f2bf(t[mi][3]);
            *(ushort4*)&Ps[(wave * 16 + lm) * 72 + mi * 16 + quad * 4] = pk;
        }
        float aq[4];
#pragma unroll
        for (int r = 0; r < 4; ++r) aq[r] = __shfl(alpha, quad * 4 + r, 64);
#pragma unroll
        for (int nt = 0; nt < 8; ++nt)
#pragma unroll
            for (int r = 0; r < 4; ++r) o_acc[nt][r] *= aq[r];
        // O += P * V  (no barrier: same-wave Ps RAW, DS in-order)
#pragma unroll
        for (int kc = 0; kc < 2; ++kc) {
            short8 ap = *(const short8*)&Ps[(wave * 16 + lm) * 72 + kc * 32 + quad * 8];
#pragma unroll
            for (int nt = 0; nt < 8; ++nt) {
                int row = nt * 16 + lm;
                int pc = (kc * 4 + quad) ^ (lm & 7);
                short8 bv = *(const short8*)&Vs[row * 64 + pc * 8];
                o_acc[nt] = mfma_bf16(ap, bv, o_acc[nt]);
            }
        }
    }
    float lq[4];
#pragma unroll
    for (int r = 0; r < 4; ++r) lq[r] = __shfl(l_i, quad * 4 + r, 64);
    const int b = bh >> 4, h = bh & 15;
#pragma unroll
    for (int nt = 0; nt < 8; ++nt)
#pragma unroll
        for (int r = 0; r < 4; ++r) {
            const int pos = q0 + wave * 16 + quad * 4 + r;
            const int col = h * 128 + nt * 16 + lm;
            R[((long)b * 1024 + pos) * 2048 + col] = f2bf(o_acc[nt][r] / lq[r]);
        }
}

extern "C" void kernel_launch(void* const* d_in, const int* in_sizes, int n_in,
                              void* d_out, int out_size, void* d_ws, size_t ws_size,
                              hipStream_t stream) {
    const float* x    = (const float*)d_in[0];
    const float* Wqkv = (const float*)d_in[2];
    const float* Wout = (const float*)d_in[3];
    const float* bout = (const float*)d_in[4];
    float* out = (float*)d_out;

    char* ws = (char*)d_ws;
    u16* x_bf  = (u16*)(ws);                 // 8MB; dead after qkv GEMM
    u16* rbuf  = x_bf;                       // reuse: written by flash
    u16* WqkvT = (u16*)(ws + (8L << 20));    // 24MB; dead after qkv GEMM
    u16* WoutT = (u16*)(ws + (32L << 20));   // 8MB
    u16* qbuf  = (u16*)(ws + (40L << 20));   // 8MB (roped)
    u16* kbuf  = (u16*)(ws + (48L << 20));   // 8MB (roped)
    u16* vtbuf = (u16*)(ws + (56L << 20));   // 8MB, vT[32][128][1024] written by gemm epilogue

    k_prep<<<8192, 256, 0, stream>>>(x, Wqkv, Wout, x_bf, WqkvT, WoutT);
    k_gemm<0><<<dim3(16, 48), 256, 0, stream>>>(x_bf, WqkvT, 2048, qbuf, kbuf, vtbuf,
                                                nullptr, nullptr);
    k_flash<<<512, 256, 0, stream>>>(qbuf, kbuf, vtbuf, rbuf);
    k_gemm<1><<<dim3(16, 16), 256, 0, stream>>>(rbuf, WoutT, 2048, nullptr, nullptr, nullptr,
                                                out, bout);
}

// Round 4
// 248.497 us; speedup vs baseline: 1.2629x; 1.0316x over previous
//
#include <hip/hip_runtime.h>
#include <math.h>

typedef unsigned short u16;
typedef unsigned int u32;
typedef __attribute__((ext_vector_type(8))) short short8;  // 8 bf16 (4 VGPR)
typedef __attribute__((ext_vector_type(4))) float f32x4;   // MFMA acc

#define DEVI __device__ __forceinline__

DEVI u16 f2bf(float x) {
    union { float f; u32 u; } un; un.f = x;
    u32 u = un.u;
    return (u16)((u + 0x7fffu + ((u >> 16) & 1u)) >> 16);  // RTNE
}
DEVI float bf2f(u16 v) {
    union { u32 u; float f; } un; un.u = ((u32)v) << 16;
    return un.f;
}
DEVI f32x4 mfma_bf16(short8 a, short8 b, f32x4 c) {
    return __builtin_amdgcn_mfma_f32_16x16x32_bf16(a, b, c, 0, 0, 0);
}
// async global->LDS, 16B/lane. LDS dest = wave-uniform base + lane*16.
DEVI void gload_lds16(const void* g, void* l) {
    __builtin_amdgcn_global_load_lds((const __attribute__((address_space(1))) u32*)g,
                                     (__attribute__((address_space(3))) u32*)l,
                                     16, 0, 0);
}

// ---------------- fused prep: x->bf16 convert + Wqkv^T + Wout^T ----------------
__global__ void k_prep(const float* __restrict__ x, const float* __restrict__ Wqkv,
                       const float* __restrict__ Wout, u16* __restrict__ x_bf,
                       u16* __restrict__ WqkvT, u16* __restrict__ WoutT) {
    __shared__ u16 tile[64][68];
    const int bid = blockIdx.x;
    if (bid < 4096) {
        long idx = ((long)bid * 256 + threadIdx.x) * 4;
        float4 v = *(const float4*)(x + idx);
        ushort4 o;
        o.x = f2bf(v.x); o.y = f2bf(v.y); o.z = f2bf(v.z); o.w = f2bf(v.w);
        *(ushort4*)(x_bf + idx) = o;
        return;
    }
    const float* in;
    u16* out;
    int R, C, bx, by;
    if (bid < 7168) {
        int lb = bid - 4096;
        in = Wqkv; out = WqkvT; R = 2048; C = 6144;
        bx = lb % 96; by = lb / 96;
    } else {
        int lb = bid - 7168;
        in = Wout; out = WoutT; R = 2048; C = 2048;
        bx = lb & 31; by = lb >> 5;
    }
    const int tx = threadIdx.x & 15, ty = threadIdx.x >> 4;
    const long r0 = (long)by * 64, c0 = (long)bx * 64;
#pragma unroll
    for (int p = 0; p < 4; ++p) {
        int r = ty + p * 16;
        float4 v = *(const float4*)(in + (r0 + r) * C + c0 + tx * 4);
        ushort4 o;
        o.x = f2bf(v.x); o.y = f2bf(v.y); o.z = f2bf(v.z); o.w = f2bf(v.w);
        *(ushort4*)&tile[r][tx * 4] = o;
    }
    __syncthreads();
#pragma unroll
    for (int p = 0; p < 4; ++p) {
        int rr = ty + p * 16;
        ushort4 o;
        o.x = tile[tx * 4 + 0][rr];
        o.y = tile[tx * 4 + 1][rr];
        o.z = tile[tx * 4 + 2][rr];
        o.w = tile[tx * 4 + 3][rr];
        *(ushort4*)(out + (c0 + rr) * R + r0 + tx * 4) = o;
    }
}

// ---------------- m97-style bf16 GEMM, XOR-swizzled LDS ----------------
// C[M,N] = A[M,K] * BT[N,K]^T.
// EPI 0: QKV epilogue — LDS tile round-trip; q/k get RoPE (HW sin/cos), v stored
//        transposed straight into vT[32][128][1024].
// EPI 1: +bias, fp32 store.
template <int EPI>
__global__ __launch_bounds__(256, 2) void k_gemm(const u16* __restrict__ A,
                                                 const u16* __restrict__ BT, int K,
                                                 u16* __restrict__ qb, u16* __restrict__ kb,
                                                 u16* __restrict__ vtb, float* __restrict__ out,
                                                 const float* __restrict__ bias) {
    __shared__ union SM {
        struct { u16 As[128 * 64]; u16 Bs[128 * 64]; } s;  // swizzled staging
        u16 T[128 * 132];                                  // epilogue tile (pad 132)
    } sm;
    const int tid = threadIdx.x;
    const int lane = tid & 63, wave = tid >> 6;
    const int lm = lane & 15, quad = lane >> 4;
    const int wm = wave >> 1, wn = wave & 1;
    const int bm = blockIdx.x, bn = blockIdx.y;

    f32x4 acc[4][4] = {};

    const int srow = lane >> 3;
    const int scb = (lane & 7) ^ srow;
    const long arow0 = (long)bm * 128;
    const long brow0 = (long)bn * 128;

    for (int k0 = 0; k0 < K; k0 += 64) {
        __syncthreads();
#pragma unroll
        for (int it = 0; it < 4; ++it) {
            int ch = wave * 4 + it;
            long r = ch * 8 + srow;
            gload_lds16(A + (arow0 + r) * K + k0 + scb * 8, (char*)sm.s.As + ch * 1024);
            gload_lds16(BT + (brow0 + r) * K + k0 + scb * 8, (char*)sm.s.Bs + ch * 1024);
        }
        __syncthreads();
#pragma unroll
        for (int ko = 0; ko < 2; ++ko) {
            short8 af[4], bf[4];
#pragma unroll
            for (int i = 0; i < 4; ++i) {
                int row = wm * 64 + i * 16 + lm;
                int pc = (ko * 4 + quad) ^ (lm & 7);
                af[i] = *(const short8*)&sm.s.As[row * 64 + pc * 8];
            }
#pragma unroll
            for (int j = 0; j < 4; ++j) {
                int row = wn * 64 + j * 16 + lm;
                int pc = (ko * 4 + quad) ^ (lm & 7);
                bf[j] = *(const short8*)&sm.s.Bs[row * 64 + pc * 8];
            }
#pragma unroll
            for (int i = 0; i < 4; ++i)
#pragma unroll
                for (int j = 0; j < 4; ++j)
                    acc[i][j] = mfma_bf16(af[i], bf[j], acc[i][j]);
        }
    }

    if constexpr (EPI == 0) {
        __syncthreads();  // all waves done reading As/Bs
#pragma unroll
        for (int i = 0; i < 4; ++i)
#pragma unroll
            for (int j = 0; j < 4; ++j) {
                const int col = wn * 64 + j * 16 + lm;
#pragma unroll
                for (int r = 0; r < 4; ++r) {
                    const int row = wm * 64 + i * 16 + quad * 4 + r;
                    sm.T[row * 132 + col] = f2bf(acc[i][j][r]);
                }
            }
        __syncthreads();
        const int which = bn >> 4, h = bn & 15, b = bm >> 3;
        const int p0 = (bm & 7) * 128;
        if (which < 2) {
            // RoPE + store to q/k buffer [bh][pos][128]
            u16* dst = which ? kb : qb;
            const long hb = ((long)(b * 16 + h)) * 1024;
            const int i0 = (tid * 4) & 63;   // c-invariant
            const int pb = tid >> 4;         // pos_l = c*16 + pb
            float inv[4];
#pragma unroll
            for (int e = 0; e < 4; ++e)
                inv[e] = exp2f(-(float)(i0 + e) * 0.20762050593045952f);  // log2(1e4)/64
#pragma unroll
            for (int c = 0; c < 8; ++c) {
                const int pos_l = c * 16 + pb;
                ushort4 cur = *(const ushort4*)&sm.T[pos_l * 132 + i0];
                ushort4 par = *(const ushort4*)&sm.T[pos_l * 132 + i0 + 64];
                const float pg = (float)(p0 + pos_l);
                ushort4 o1, o2;
                const u16* cp = (const u16*)&cur;
                const u16* pp = (const u16*)&par;
                u16* o1p = (u16*)&o1;
                u16* o2p = (u16*)&o2;
#pragma unroll
                for (int e = 0; e < 4; ++e) {
                    float th = pg * inv[e];
                    float sv = __sinf(th), cv = __cosf(th);  // v_sin/v_cos, |th|<=1023
                    float x1 = bf2f(cp[e]), x2 = bf2f(pp[e]);
                    o1p[e] = f2bf(x1 * cv - x2 * sv);
                    o2p[e] = f2bf(x2 * cv + x1 * sv);
                }
                const long rowb = (hb + p0 + pos_l) * 128;
                *(ushort4*)(dst + rowb + i0) = o1;
                *(ushort4*)(dst + rowb + i0 + 64) = o2;
            }
        } else {
            // V: store transposed into vT[32][128][1024]
            const long vrow = ((long)(b * 16 + h)) * 128;
#pragma unroll
            for (int c = 0; c < 8; ++c) {
                const int lin = c * 2048 + tid * 8;
                const int dk = lin >> 7;
                const int ps = lin & 127;
                ushort4 o1, o2;
                u16* o1p = (u16*)&o1;
                u16* o2p = (u16*)&o2;
#pragma unroll
                for (int e = 0; e < 4; ++e) {
                    o1p[e] = sm.T[(ps + e) * 132 + dk];
                    o2p[e] = sm.T[(ps + 4 + e) * 132 + dk];
                }
                u16* dst = vtb + (vrow + dk) * 1024 + p0 + ps;
                *(ushort4*)dst = o1;
                *(ushort4*)(dst + 4) = o2;
            }
        }
    } else {
        float bv[4];
#pragma unroll
        for (int j = 0; j < 4; ++j) bv[j] = bias[bn * 128 + wn * 64 + j * 16 + lm];
#pragma unroll
        for (int i = 0; i < 4; ++i) {
#pragma unroll
            for (int r = 0; r < 4; ++r) {
                const int row = bm * 128 + wm * 64 + i * 16 + quad * 4 + r;
#pragma unroll
                for (int j = 0; j < 4; ++j) {
                    const int col = bn * 128 + wn * 64 + j * 16 + lm;
                    out[(long)row * 2048 + col] = acc[i][j][r] + bv[j];
                }
            }
        }
    }
}

// ---------------- flash attention (causal), S^T = K*Q^T, swizzled LDS ----------------
__global__ __launch_bounds__(256, 2) void k_flash(const u16* __restrict__ Q,
                                                  const u16* __restrict__ Kb,
                                                  const u16* __restrict__ VT,
                                                  u16* __restrict__ R) {
    __shared__ u16 Ks[64 * 128];  // [key 64][d 128], swizzled mask 15
    __shared__ u16 Vs[128 * 64];  // [d 128][key 64], swizzled mask 7
    __shared__ u16 Ps[64 * 72];   // [q 64][key 64 + 8 pad]
    const int tid = threadIdx.x;
    const int lane = tid & 63, wave = tid >> 6;
    const int lm = lane & 15, quad = lane >> 4;
    const int id = blockIdx.x;
    const int g = id >> 8, rem = id & 255;
    const int bh = rem >> 3, s = rem & 7;
    const int qt = g ? (15 - s) : s;
    const long qkbase = (long)bh * 1024 * 128;
    const long vtbase = (long)bh * 128 * 1024;
    const int q0 = qt * 64;

    short8 qf[4];
    {
        const u16* qrow = Q + qkbase + (long)(q0 + wave * 16 + lm) * 128 + quad * 8;
#pragma unroll
        for (int kc = 0; kc < 4; ++kc) qf[kc] = *(const short8*)(qrow + kc * 32);
    }

    f32x4 o_acc[8] = {};
    float m_i = -INFINITY, l_i = 0.f;
    const float cl2e = 0.08838834764831845f * 1.4426950408889634f;  // 1/sqrt(128)*log2(e)

    const int kr = lane >> 4;
    const int vr = lane >> 3;
    const int vcb = (lane & 7) ^ vr;

    for (int kt = 0; kt <= qt; ++kt) {
        __syncthreads();
        {
#pragma unroll
            for (int it = 0; it < 4; ++it) {
                int ch = wave * 4 + it;
                int krow = ch * 4 + kr;
                int kchunk = (lane & 15) ^ (krow & 15);
                gload_lds16(Kb + qkbase + (long)(kt * 64 + krow) * 128 + kchunk * 8,
                            (char*)Ks + ch * 1024);
                int vrow = ch * 8 + vr;
                gload_lds16(VT + vtbase + (long)vrow * 1024 + kt * 64 + vcb * 8,
                            (char*)Vs + ch * 1024);
            }
        }
        __syncthreads();

        f32x4 s_acc[4] = {};
#pragma unroll
        for (int kc = 0; kc < 4; ++kc) {
#pragma unroll
            for (int mi = 0; mi < 4; ++mi) {
                int row = mi * 16 + lm;
                int pc = (kc * 4 + quad) ^ lm;
                short8 ak = *(const short8*)&Ks[row * 128 + pc * 8];
                s_acc[mi] = mfma_bf16(ak, qf[kc], s_acc[mi]);
            }
        }
        const int qg = q0 + wave * 16 + lm;
        float t[4][4];
        float cmax = -INFINITY;
#pragma unroll
        for (int mi = 0; mi < 4; ++mi)
#pragma unroll
            for (int r = 0; r < 4; ++r) {
                int kg = kt * 64 + mi * 16 + quad * 4 + r;
                float val = (kg <= qg) ? s_acc[mi][r] * cl2e : -INFINITY;
                t[mi][r] = val;
                cmax = fmaxf(cmax, val);
            }
        cmax = fmaxf(cmax, __shfl_xor(cmax, 16));
        cmax = fmaxf(cmax, __shfl_xor(cmax, 32));
        float m_new = fmaxf(m_i, cmax);
        float alpha = exp2f(m_i - m_new);
        float csum = 0.f;
#pragma unroll
        for (int mi = 0; mi < 4; ++mi)
#pragma unroll
            for (int r = 0; r < 4; ++r) {
                float p = exp2f(t[mi][r] - m_new);
                t[mi][r] = p;
                csum += p;
            }
        csum += __shfl_xor(csum, 16);
        csum += __shfl_xor(csum, 32);
        l_i = l_i * alpha + csum;
        m_i = m_new;
#pragma unroll
        for (int mi = 0; mi < 4; ++mi) {
            ushort4 pk;
            pk.x = f2bf(t[mi][0]); pk.y = f2bf(t[mi][1]);
            pk.z = f2bf(t[mi][2]); pk.w = f2bf(t[mi][3]);
            *(ushort4*)&Ps[(wave * 16 + lm) * 72 + mi * 16 + quad * 4] = pk;
        }
        float aq[4];
#pragma unroll
        for (int r = 0; r < 4; ++r) aq[r] = __shfl(alpha, quad * 4 + r, 64);
#pragma unroll
        for (int nt = 0; nt < 8; ++nt)
#pragma unroll
            for (int r = 0; r < 4; ++r) o_acc[nt][r] *= aq[r];
#pragma unroll
        for (int kc = 0; kc < 2; ++kc) {
            short8 ap = *(const short8*)&Ps[(wave * 16 + lm) * 72 + kc * 32 + quad * 8];
#pragma unroll
            for (int nt = 0; nt < 8; ++nt) {
                int row = nt * 16 + lm;
                int pc = (kc * 4 + quad) ^ (lm & 7);
                short8 bv = *(const short8*)&Vs[row * 64 + pc * 8];
                o_acc[nt] = mfma_bf16(ap, bv, o_acc[nt]);
            }
        }
    }
    float lq[4];
#pragma unroll
    for (int r = 0; r < 4; ++r) lq[r] = __shfl(l_i, quad * 4 + r, 64);
    const int b = bh >> 4, h = bh & 15;
#pragma unroll
    for (int nt = 0; nt < 8; ++nt)
#pragma unroll
        for (int r = 0; r < 4; ++r) {
            const int pos = q0 + wave * 16 + quad * 4 + r;
            const int col = h * 128 + nt * 16 + lm;
            R[((long)b * 1024 + pos) * 2048 + col] = f2bf(o_acc[nt][r] / lq[r]);
        }
}

extern "C" void kernel_launch(void* const* d_in, const int* in_sizes, int n_in,
                              void* d_out, int out_size, void* d_ws, size_t ws_size,
                              hipStream_t stream) {
    const float* x    = (const float*)d_in[0];
    const float* Wqkv = (const float*)d_in[2];
    const float* Wout = (const float*)d_in[3];
    const float* bout = (const float*)d_in[4];
    float* out = (float*)d_out;

    char* ws = (char*)d_ws;
    u16* x_bf  = (u16*)(ws);                 // 8MB; dead after qkv GEMM
    u16* rbuf  = x_bf;                       // reuse: written by flash
    u16* WqkvT = (u16*)(ws + (8L << 20));    // 24MB
    u16* WoutT = (u16*)(ws + (32L << 20));   // 8MB
    u16* qbuf  = (u16*)(ws + (40L << 20));   // 8MB (roped)
    u16* kbuf  = (u16*)(ws + (48L << 20));   // 8MB (roped)
    u16* vtbuf = (u16*)(ws + (56L << 20));   // 8MB, vT[32][128][1024]

    k_prep<<<8192, 256, 0, stream>>>(x, Wqkv, Wout, x_bf, WqkvT, WoutT);
    k_gemm<0><<<dim3(16, 48), 256, 0, stream>>>(x_bf, WqkvT, 2048, qbuf, kbuf, vtbuf,
                                                nullptr, nullptr);
    k_flash<<<512, 256, 0, stream>>>(qbuf, kbuf, vtbuf, rbuf);
    k_gemm<1><<<dim3(16, 16), 256, 0, stream>>>(rbuf, WoutT, 2048, nullptr, nullptr, nullptr,
                                                out, bout);
}

// Round 5
// 239.320 us; speedup vs baseline: 1.3113x; 1.0383x over previous
//
#include <hip/hip_runtime.h>
#include <math.h>

typedef unsigned short u16;
typedef unsigned int u32;
typedef __attribute__((ext_vector_type(8))) short short8;  // 8 bf16 (4 VGPR)
typedef __attribute__((ext_vector_type(4))) float f32x4;   // MFMA acc

#define DEVI __device__ __forceinline__

DEVI u16 f2bf(float x) {
    union { float f; u32 u; } un; un.f = x;
    u32 u = un.u;
    return (u16)((u + 0x7fffu + ((u >> 16) & 1u)) >> 16);  // RTNE
}
DEVI float bf2f(u16 v) {
    union { u32 u; float f; } un; un.u = ((u32)v) << 16;
    return un.f;
}
DEVI f32x4 mfma_bf16(short8 a, short8 b, f32x4 c) {
    return __builtin_amdgcn_mfma_f32_16x16x32_bf16(a, b, c, 0, 0, 0);
}
// async global->LDS, 16B/lane. LDS dest = wave-uniform base + lane*16.
DEVI void gload_lds16(const void* g, void* l) {
    __builtin_amdgcn_global_load_lds((const __attribute__((address_space(1))) u32*)g,
                                     (__attribute__((address_space(3))) u32*)l,
                                     16, 0, 0);
}

// ---------------- fused prep: x->bf16 convert + Wqkv^T + Wout^T ----------------
__global__ void k_prep(const float* __restrict__ x, const float* __restrict__ Wqkv,
                       const float* __restrict__ Wout, u16* __restrict__ x_bf,
                       u16* __restrict__ WqkvT, u16* __restrict__ WoutT) {
    __shared__ u16 tile[64][68];
    const int bid = blockIdx.x;
    if (bid < 4096) {
        long idx = ((long)bid * 256 + threadIdx.x) * 4;
        float4 v = *(const float4*)(x + idx);
        ushort4 o;
        o.x = f2bf(v.x); o.y = f2bf(v.y); o.z = f2bf(v.z); o.w = f2bf(v.w);
        *(ushort4*)(x_bf + idx) = o;
        return;
    }
    const float* in;
    u16* out;
    int R, C, bx, by;
    if (bid < 7168) {
        int lb = bid - 4096;
        in = Wqkv; out = WqkvT; R = 2048; C = 6144;
        bx = lb % 96; by = lb / 96;
    } else {
        int lb = bid - 7168;
        in = Wout; out = WoutT; R = 2048; C = 2048;
        bx = lb & 31; by = lb >> 5;
    }
    const int tx = threadIdx.x & 15, ty = threadIdx.x >> 4;
    const long r0 = (long)by * 64, c0 = (long)bx * 64;
#pragma unroll
    for (int p = 0; p < 4; ++p) {
        int r = ty + p * 16;
        float4 v = *(const float4*)(in + (r0 + r) * C + c0 + tx * 4);
        ushort4 o;
        o.x = f2bf(v.x); o.y = f2bf(v.y); o.z = f2bf(v.z); o.w = f2bf(v.w);
        *(ushort4*)&tile[r][tx * 4] = o;
    }
    __syncthreads();
#pragma unroll
    for (int p = 0; p < 4; ++p) {
        int rr = ty + p * 16;
        ushort4 o;
        o.x = tile[tx * 4 + 0][rr];
        o.y = tile[tx * 4 + 1][rr];
        o.z = tile[tx * 4 + 2][rr];
        o.w = tile[tx * 4 + 3][rr];
        *(ushort4*)(out + (c0 + rr) * R + r0 + tx * 4) = o;
    }
}

// ---------------- m97-style bf16 GEMM, XOR-swizzled LDS, templated tile-M ----------------
// C[bm*TM..+TM, bn*128..+128] = A[M,K] * BT[N,K]^T.
// EPI 0 (TM=128): QKV epilogue — RoPE q/k, v transposed into vT[32][128][1024].
// EPI 1 (TM=64):  +bias, fp32 store (smaller tile -> 512 blocks -> 2-3/CU).
template <int EPI, int TM>
__global__ __launch_bounds__(256, 3) void k_gemm(const u16* __restrict__ A,
                                                 const u16* __restrict__ BT, int K,
                                                 u16* __restrict__ qb, u16* __restrict__ kb,
                                                 u16* __restrict__ vtb, float* __restrict__ out,
                                                 const float* __restrict__ bias) {
    constexpr int MI = TM / 32;       // A-frags per wave (4 for TM=128, 2 for TM=64)
    constexpr int CA = TM / 32;       // A staging chunks per wave (nchA = TM/8, /4 waves)
    __shared__ __align__(16) union SM {
        struct { u16 As[TM * 64]; u16 Bs[128 * 64]; } s;   // swizzled staging
        u16 T[EPI == 0 ? 128 * 132 : 8];                   // epilogue tile (pad 132)
    } sm;
    const int tid = threadIdx.x;
    const int lane = tid & 63, wave = tid >> 6;
    const int lm = lane & 15, quad = lane >> 4;
    const int wm = wave >> 1, wn = wave & 1;
    const int bm = blockIdx.x, bn = blockIdx.y;

    f32x4 acc[MI][4] = {};

    const int srow = lane >> 3;
    const int scb = (lane & 7) ^ srow;
    const long arow0 = (long)bm * TM;
    const long brow0 = (long)bn * 128;

    for (int k0 = 0; k0 < K; k0 += 64) {
        __syncthreads();
#pragma unroll
        for (int it = 0; it < CA; ++it) {
            int ch = wave * CA + it;
            long r = ch * 8 + srow;
            gload_lds16(A + (arow0 + r) * K + k0 + scb * 8, (char*)sm.s.As + ch * 1024);
        }
#pragma unroll
        for (int it = 0; it < 4; ++it) {
            int ch = wave * 4 + it;
            long r = ch * 8 + srow;
            gload_lds16(BT + (brow0 + r) * K + k0 + scb * 8, (char*)sm.s.Bs + ch * 1024);
        }
        __syncthreads();
#pragma unroll
        for (int ko = 0; ko < 2; ++ko) {
            short8 af[MI], bf[4];
#pragma unroll
            for (int i = 0; i < MI; ++i) {
                int row = wm * (TM / 2) + i * 16 + lm;
                int pc = (ko * 4 + quad) ^ (lm & 7);
                af[i] = *(const short8*)&sm.s.As[row * 64 + pc * 8];
            }
#pragma unroll
            for (int j = 0; j < 4; ++j) {
                int row = wn * 64 + j * 16 + lm;
                int pc = (ko * 4 + quad) ^ (lm & 7);
                bf[j] = *(const short8*)&sm.s.Bs[row * 64 + pc * 8];
            }
#pragma unroll
            for (int i = 0; i < MI; ++i)
#pragma unroll
                for (int j = 0; j < 4; ++j)
                    acc[i][j] = mfma_bf16(af[i], bf[j], acc[i][j]);
        }
    }

    if constexpr (EPI == 0) {
        __syncthreads();  // all waves done reading As/Bs
#pragma unroll
        for (int i = 0; i < MI; ++i)
#pragma unroll
            for (int j = 0; j < 4; ++j) {
                const int col = wn * 64 + j * 16 + lm;
#pragma unroll
                for (int r = 0; r < 4; ++r) {
                    const int row = wm * 64 + i * 16 + quad * 4 + r;
                    sm.T[row * 132 + col] = f2bf(acc[i][j][r]);
                }
            }
        __syncthreads();
        const int which = bn >> 4, h = bn & 15, b = bm >> 3;
        const int p0 = (bm & 7) * 128;
        if (which < 2) {
            // RoPE + store to q/k buffer [bh][pos][128]
            u16* dst = which ? kb : qb;
            const long hb = ((long)(b * 16 + h)) * 1024;
            const int i0 = (tid * 4) & 63;   // c-invariant
            const int pb = tid >> 4;         // pos_l = c*16 + pb
            float inv[4];
#pragma unroll
            for (int e = 0; e < 4; ++e)
                inv[e] = exp2f(-(float)(i0 + e) * 0.20762050593045952f);  // log2(1e4)/64
#pragma unroll
            for (int c = 0; c < 8; ++c) {
                const int pos_l = c * 16 + pb;
                ushort4 cur = *(const ushort4*)&sm.T[pos_l * 132 + i0];
                ushort4 par = *(const ushort4*)&sm.T[pos_l * 132 + i0 + 64];
                const float pg = (float)(p0 + pos_l);
                ushort4 o1, o2;
                const u16* cp = (const u16*)&cur;
                const u16* pp = (const u16*)&par;
                u16* o1p = (u16*)&o1;
                u16* o2p = (u16*)&o2;
#pragma unroll
                for (int e = 0; e < 4; ++e) {
                    float th = pg * inv[e];
                    float sv = __sinf(th), cv = __cosf(th);  // v_sin/v_cos, |th|<=1023
                    float x1 = bf2f(cp[e]), x2 = bf2f(pp[e]);
                    o1p[e] = f2bf(x1 * cv - x2 * sv);
                    o2p[e] = f2bf(x2 * cv + x1 * sv);
                }
                const long rowb = (hb + p0 + pos_l) * 128;
                *(ushort4*)(dst + rowb + i0) = o1;
                *(ushort4*)(dst + rowb + i0 + 64) = o2;
            }
        } else {
            // V: store transposed into vT[32][128][1024]
            const long vrow = ((long)(b * 16 + h)) * 128;
#pragma unroll
            for (int c = 0; c < 8; ++c) {
                const int lin = c * 2048 + tid * 8;
                const int dk = lin >> 7;
                const int ps = lin & 127;
                ushort4 o1, o2;
                u16* o1p = (u16*)&o1;
                u16* o2p = (u16*)&o2;
#pragma unroll
                for (int e = 0; e < 4; ++e) {
                    o1p[e] = sm.T[(ps + e) * 132 + dk];
                    o2p[e] = sm.T[(ps + 4 + e) * 132 + dk];
                }
                u16* dst = vtb + (vrow + dk) * 1024 + p0 + ps;
                *(ushort4*)dst = o1;
                *(ushort4*)(dst + 4) = o2;
            }
        }
    } else {
        float bv[4];
#pragma unroll
        for (int j = 0; j < 4; ++j) bv[j] = bias[bn * 128 + wn * 64 + j * 16 + lm];
#pragma unroll
        for (int i = 0; i < MI; ++i) {
#pragma unroll
            for (int r = 0; r < 4; ++r) {
                const int row = bm * TM + wm * (TM / 2) + i * 16 + quad * 4 + r;
#pragma unroll
                for (int j = 0; j < 4; ++j) {
                    const int col = bn * 128 + wn * 64 + j * 16 + lm;
                    out[(long)row * 2048 + col] = acc[i][j][r] + bv[j];
                }
            }
        }
    }
}

// ---------------- flash attention (causal), S^T = K*Q^T, swizzled LDS ----------------
__global__ __launch_bounds__(256, 3) void k_flash(const u16* __restrict__ Q,
                                                  const u16* __restrict__ Kb,
                                                  const u16* __restrict__ VT,
                                                  u16* __restrict__ R) {
    __shared__ u16 Ks[64 * 128];  // [key 64][d 128], swizzled mask 15
    __shared__ u16 Vs[128 * 64];  // [d 128][key 64], swizzled mask 7
    __shared__ u16 Ps[64 * 72];   // [q 64][key 64 + 8 pad]
    const int tid = threadIdx.x;
    const int lane = tid & 63, wave = tid >> 6;
    const int lm = lane & 15, quad = lane >> 4;
    const int id = blockIdx.x;
    const int g = id >> 8, rem = id & 255;
    const int bh = rem >> 3, s = rem & 7;
    const int qt = g ? (15 - s) : s;
    const long qkbase = (long)bh * 1024 * 128;
    const long vtbase = (long)bh * 128 * 1024;
    const int q0 = qt * 64;

    short8 qf[4];
    {
        const u16* qrow = Q + qkbase + (long)(q0 + wave * 16 + lm) * 128 + quad * 8;
#pragma unroll
        for (int kc = 0; kc < 4; ++kc) qf[kc] = *(const short8*)(qrow + kc * 32);
    }

    f32x4 o_acc[8] = {};
    float m_i = -INFINITY, l_i = 0.f;
    const float cl2e = 0.08838834764831845f * 1.4426950408889634f;  // 1/sqrt(128)*log2(e)

    const int kr = lane >> 4;
    const int vr = lane >> 3;
    const int vcb = (lane & 7) ^ vr;

    for (int kt = 0; kt <= qt; ++kt) {
        __syncthreads();
        {
#pragma unroll
            for (int it = 0; it < 4; ++it) {
                int ch = wave * 4 + it;
                int krow = ch * 4 + kr;
                int kchunk = (lane & 15) ^ (krow & 15);
                gload_lds16(Kb + qkbase + (long)(kt * 64 + krow) * 128 + kchunk * 8,
                            (char*)Ks + ch * 1024);
                int vrow = ch * 8 + vr;
                gload_lds16(VT + vtbase + (long)vrow * 1024 + kt * 64 + vcb * 8,
                            (char*)Vs + ch * 1024);
            }
        }
        __syncthreads();

        f32x4 s_acc[4] = {};
#pragma unroll
        for (int kc = 0; kc < 4; ++kc) {
#pragma unroll
            for (int mi = 0; mi < 4; ++mi) {
                int row = mi * 16 + lm;
                int pc = (kc * 4 + quad) ^ lm;
                short8 ak = *(const short8*)&Ks[row * 128 + pc * 8];
                s_acc[mi] = mfma_bf16(ak, qf[kc], s_acc[mi]);
            }
        }
        const int qg = q0 + wave * 16 + lm;
        float t[4][4];
        float cmax = -INFINITY;
#pragma unroll
        for (int mi = 0; mi < 4; ++mi)
#pragma unroll
            for (int r = 0; r < 4; ++r) {
                int kg = kt * 64 + mi * 16 + quad * 4 + r;
                float val = (kg <= qg) ? s_acc[mi][r] * cl2e : -INFINITY;
                t[mi][r] = val;
                cmax = fmaxf(cmax, val);
            }
        cmax = fmaxf(cmax, __shfl_xor(cmax, 16));
        cmax = fmaxf(cmax, __shfl_xor(cmax, 32));
        float m_new = fmaxf(m_i, cmax);
        float alpha = exp2f(m_i - m_new);
        float csum = 0.f;
#pragma unroll
        for (int mi = 0; mi < 4; ++mi)
#pragma unroll
            for (int r = 0; r < 4; ++r) {
                float p = exp2f(t[mi][r] - m_new);
                t[mi][r] = p;
                csum += p;
            }
        csum += __shfl_xor(csum, 16);
        csum += __shfl_xor(csum, 32);
        l_i = l_i * alpha + csum;
        m_i = m_new;
#pragma unroll
        for (int mi = 0; mi < 4; ++mi) {
            ushort4 pk;
            pk.x = f2bf(t[mi][0]); pk.y = f2bf(t[mi][1]);
            pk.z = f2bf(t[mi][2]); pk.w = f2bf(t[mi][3]);
            *(ushort4*)&Ps[(wave * 16 + lm) * 72 + mi * 16 + quad * 4] = pk;
        }
        float aq[4];
#pragma unroll
        for (int r = 0; r < 4; ++r) aq[r] = __shfl(alpha, quad * 4 + r, 64);
#pragma unroll
        for (int nt = 0; nt < 8; ++nt)
#pragma unroll
            for (int r = 0; r < 4; ++r) o_acc[nt][r] *= aq[r];
#pragma unroll
        for (int kc = 0; kc < 2; ++kc) {
            short8 ap = *(const short8*)&Ps[(wave * 16 + lm) * 72 + kc * 32 + quad * 8];
#pragma unroll
            for (int nt = 0; nt < 8; ++nt) {
                int row = nt * 16 + lm;
                int pc = (kc * 4 + quad) ^ (lm & 7);
                short8 bv = *(const short8*)&Vs[row * 64 + pc * 8];
                o_acc[nt] = mfma_bf16(ap, bv, o_acc[nt]);
            }
        }
    }
    float lq[4];
#pragma unroll
    for (int r = 0; r < 4; ++r) lq[r] = __shfl(l_i, quad * 4 + r, 64);
    const int b = bh >> 4, h = bh & 15;
#pragma unroll
    for (int nt = 0; nt < 8; ++nt)
#pragma unroll
        for (int r = 0; r < 4; ++r) {
            const int pos = q0 + wave * 16 + quad * 4 + r;
            const int col = h * 128 + nt * 16 + lm;
            R[((long)b * 1024 + pos) * 2048 + col] = f2bf(o_acc[nt][r] / lq[r]);
        }
}

extern "C" void kernel_launch(void* const* d_in, const int* in_sizes, int n_in,
                              void* d_out, int out_size, void* d_ws, size_t ws_size,
                              hipStream_t stream) {
    const float* x    = (const float*)d_in[0];
    const float* Wqkv = (const float*)d_in[2];
    const float* Wout = (const float*)d_in[3];
    const float* bout = (const float*)d_in[4];
    float* out = (float*)d_out;

    char* ws = (char*)d_ws;
    u16* x_bf  = (u16*)(ws);                 // 8MB; dead after qkv GEMM
    u16* rbuf  = x_bf;                       // reuse: written by flash
    u16* WqkvT = (u16*)(ws + (8L << 20));    // 24MB
    u16* WoutT = (u16*)(ws + (32L << 20));   // 8MB
    u16* qbuf  = (u16*)(ws + (40L << 20));   // 8MB (roped)
    u16* kbuf  = (u16*)(ws + (48L << 20));   // 8MB (roped)
    u16* vtbuf = (u16*)(ws + (56L << 20));   // 8MB, vT[32][128][1024]

    k_prep<<<8192, 256, 0, stream>>>(x, Wqkv, Wout, x_bf, WqkvT, WoutT);
    k_gemm<0, 128><<<dim3(16, 48), 256, 0, stream>>>(x_bf, WqkvT, 2048, qbuf, kbuf, vtbuf,
                                                     nullptr, nullptr);
    k_flash<<<512, 256, 0, stream>>>(qbuf, kbuf, vtbuf, rbuf);
    k_gemm<1, 64><<<dim3(32, 16), 256, 0, stream>>>(rbuf, WoutT, 2048, nullptr, nullptr,
                                                    nullptr, out, bout);
}